// Round 5
// baseline (431.229 us; speedup 1.0000x reference)
//
#include <hip/hip_runtime.h>
#include <hip/hip_fp16.h>

// ---- R6 CSR-build constants (verbatim; load-bearing for agg locality) ----
#define NBLK_BIN 256   // bin blocks; chunking identical to r3/r5/r6 -> same per-cell counts
#define NBKT 196       // ceil(100000/512) dst-buckets
#define BWIN 512       // nodes per bucket
#define CAP 128        // slots per (block,bucket); lambda=63.8, +8 sigma -> no overflow

// NOTE (R8/R9 post-mortem): R6's exact CSR build is load-bearing for agg
// locality. Keep CSR output structure EXACT.
// NOTE (R10): no __builtin_nontemporal anywhere (srcs/gemm-input have L1 reuse).
// R11 (WIN -22us): gemm34 fusion + L4L5 fusion.
// R12 (WIN -4.5us + bottleneck flip): uint4 agg gathers; aggs all <56us now.
// R13: gemm34 was the top dispatch (57us) and is LDS-ISSUE-bound (448 b32
// ds_reads/thread; ~36us of per-CU LDS issue; VALUBusy 33%, HBM 3%). Rewrite:
// 4 nodes/thread (4x weight-LDS amortization), float4 LDS reads (b128),
// k-chunk-major weight layouts + {j2,j2+16,j2+32,j2+48} column split (2-way
// banks = free), hb chunk-XOR swizzle (conflict-free). Per-column fp32
// accumulation order and rounding identical -> numerics unchanged.

typedef unsigned int uint;

union U32H2 { uint u; __half2 h; };

__device__ inline float2 h2_to_f2(uint u) {
    U32H2 c; c.u = u;
    return __half22float2(c.h);
}
__device__ inline uint f2_to_h2(float a, float b) {
    U32H2 c; c.h = __floats2half2_rn(a, b);
    return c.u;
}

// ---------------- CSR build: bin pass (R6 verbatim: 1024 thr, no global atomics) ----------------
__global__ __launch_bounds__(1024) void bin_kernel(const int* __restrict__ src,
                                                   const int* __restrict__ dst,
                                                   int2* __restrict__ pairs,
                                                   int* __restrict__ blkcnt, int e) {
    __shared__ int lcnt[NBKT];
    int blk = blockIdx.x, tid = threadIdx.x;
    for (int t = tid; t < NBKT; t += 1024) lcnt[t] = 0;
    __syncthreads();
    int chunk = (e + NBLK_BIN - 1) / NBLK_BIN;
    int base = blk * chunk;
    int end = min(e, base + chunk);
    for (int i = base + tid; i < end; i += 1024) {
        int s = src[i], d = dst[i];
        int b = d >> 9;
        int pos = atomicAdd(&lcnt[b], 1);
        if (pos < CAP) pairs[((size_t)blk * NBKT + b) * CAP + pos] = make_int2(s, d);
    }
    __syncthreads();
    for (int t = tid; t < NBKT; t += 1024) blkcnt[blk * NBKT + t] = min(lcnt[t], CAP);
}

// ---------------- fused fill: in-block bucket base + counts + scan + cnt/rowptr/dinv + srcs ----
__global__ __launch_bounds__(1024) void fill_kernel(const int2* __restrict__ pairs,
                                                    const int* __restrict__ blkcnt,
                                                    int* __restrict__ srcs,
                                                    int* __restrict__ cnt,
                                                    int* __restrict__ rowptr,
                                                    float* __restrict__ dinv, int n) {
    __shared__ int lc[BWIN];
    __shared__ int ps[BWIN];
    __shared__ int sm[NBLK_BIN];
    __shared__ int gbase_s;
    int b = blockIdx.x, tid = threadIdx.x;
    int nbase = b << 9;
    if (tid < BWIN) lc[tid] = 0;
    for (int t = tid; t < NBLK_BIN; t += 1024) sm[t] = blkcnt[t * NBKT + b];
    if (tid == 0) gbase_s = 0;
    __syncthreads();
    // bucket base: sum over all bin-blocks of all buckets b' < b (L2-hot 200KB array)
    {
        long long tot = (long long)NBLK_BIN * b;
        int lsum = 0;
        for (long long j = tid; j < tot; j += 1024) {
            int blk = (int)(j / b);
            int bp  = (int)(j - (long long)blk * b);
            lsum += blkcnt[blk * NBKT + bp];
        }
        for (int o = 32; o > 0; o >>= 1) lsum += __shfl_down(lsum, o, 64);
        if ((tid & 63) == 0 && lsum != 0) atomicAdd(&gbase_s, lsum);
    }
    int wave = tid >> 6, lane = tid & 63;
    // pass 1: per-node counts (16 waves over 256 cells)
    for (int blk = wave; blk < NBLK_BIN; blk += 16) {
        int m = sm[blk];
        const int2* p = pairs + ((size_t)blk * NBKT + b) * CAP;
        for (int i = lane; i < m; i += 64) atomicAdd(&lc[p[i].y - nbase], 1);
    }
    __syncthreads();
    // exclusive scan of 512 counts
    int myc = (tid < BWIN) ? lc[tid] : 0;
    if (tid < BWIN) ps[tid] = myc;
    __syncthreads();
    for (int off = 1; off < BWIN; off <<= 1) {
        int t = 0;
        if (tid < BWIN && tid >= off) t = ps[tid - off];
        __syncthreads();
        if (tid < BWIN) ps[tid] += t;
        __syncthreads();
    }
    int gbase = gbase_s;
    if (tid < BWIN) {
        int ex = ps[tid] - myc;
        int vtx = nbase + tid;
        if (vtx < n) {
            cnt[vtx] = myc;
            rowptr[vtx] = gbase + ex;
            dinv[vtx] = rsqrtf(1.0f + (float)myc);   // +1: self-loop
        }
    }
    __syncthreads();
    if (tid < BWIN) lc[tid] = ps[tid] - myc;   // reuse as bucket-relative cursor
    __syncthreads();
    // pass 2: place srcs (contiguous monotone span for this bucket)
    for (int blk = wave; blk < NBLK_BIN; blk += 16) {
        int m = sm[blk];
        const int2* p = pairs + ((size_t)blk * NBKT + b) * CAP;
        for (int i = lane; i < m; i += 64) {
            int2 e2 = p[i];
            int o = atomicAdd(&lc[e2.y - nbase], 1);
            srcs[gbase + o] = e2.x;
        }
    }
}

// ---------------- input feature build: half, stride 4 uints, pre-scaled by dinv ----------------

__global__ __launch_bounds__(256) void build_x0_h_kernel(const float* __restrict__ coords,
                                                         const int* __restrict__ at,
                                                         const float* __restrict__ emb,
                                                         const float* __restrict__ dinv,
                                                         uint* __restrict__ x, int n) {
    int v = blockIdx.x * 256 + threadIdx.x;
    if (v >= n) return;
    float dv = dinv[v];
    float c0 = coords[3 * v + 0] * dv;
    float c1 = coords[3 * v + 1] * dv;
    float c2 = coords[3 * v + 2] * dv;
    int t = at[v];
    float e0 = emb[3 * t + 0] * dv;
    float e1 = emb[3 * t + 1] * dv;
    float e2 = emb[3 * t + 2] * dv;
    uint* row = x + (size_t)v * 4;
    row[0] = f2_to_h2(c0, c1);
    row[1] = f2_to_h2(c2, e0);
    row[2] = f2_to_h2(e1, e2);
    row[3] = 0;
}

// ---------------- R12 vectorized packed-half aggregation (verbatim) ----------------
template <int TPN, bool HAS_BIAS, bool RELU>
__global__ __launch_bounds__(256) void agg_v4_kernel(const uint* __restrict__ in_,
                                                     const float* __restrict__ dinv,
                                                     const int* __restrict__ rowptr,
                                                     const int* __restrict__ cnt,
                                                     const int* __restrict__ srcs,
                                                     const float* __restrict__ bias,
                                                     uint* __restrict__ out_, int n) {
    const uint4* in = (const uint4*)in_;
    uint4* out = (uint4*)out_;
    int gid = blockIdx.x * 256 + threadIdx.x;
    int v = gid / TPN, q = gid % TPN;
    if (v >= n) return;
    float ax[4], ay[4];
    {
        uint4 s0 = in[(size_t)v * TPN + q];
        uint su[4] = {s0.x, s0.y, s0.z, s0.w};
#pragma unroll
        for (int u = 0; u < 4; ++u) { float2 f = h2_to_f2(su[u]); ax[u] = f.x; ay[u] = f.y; }
    }
    int start = rowptr[v];
    int len = cnt[v];
    int k = 0;
    for (; k + 4 <= len; k += 4) {
        int sA = srcs[start + k];
        int sB = srcs[start + k + 1];
        int sC = srcs[start + k + 2];
        int sD = srcs[start + k + 3];
        uint4 fA = in[(size_t)sA * TPN + q];
        uint4 fB = in[(size_t)sB * TPN + q];
        uint4 fC = in[(size_t)sC * TPN + q];
        uint4 fD = in[(size_t)sD * TPN + q];
        uint ua[4] = {fA.x, fA.y, fA.z, fA.w};
        uint ub[4] = {fB.x, fB.y, fB.z, fB.w};
        uint uc[4] = {fC.x, fC.y, fC.z, fC.w};
        uint ud[4] = {fD.x, fD.y, fD.z, fD.w};
#pragma unroll
        for (int u = 0; u < 4; ++u) {
            float2 a = h2_to_f2(ua[u]);
            float2 b = h2_to_f2(ub[u]);
            float2 c = h2_to_f2(uc[u]);
            float2 d = h2_to_f2(ud[u]);
            ax[u] += (a.x + b.x) + (c.x + d.x);
            ay[u] += (a.y + b.y) + (c.y + d.y);
        }
    }
    for (; k < len; ++k) {
        int s = srcs[start + k];
        uint4 f = in[(size_t)s * TPN + q];
        uint uu[4] = {f.x, f.y, f.z, f.w};
#pragma unroll
        for (int u = 0; u < 4; ++u) { float2 t = h2_to_f2(uu[u]); ax[u] += t.x; ay[u] += t.y; }
    }
    float dv = dinv[v];
#pragma unroll
    for (int u = 0; u < 4; ++u) {
        ax[u] *= dv; ay[u] *= dv;
        if (HAS_BIAS) { ax[u] += bias[8 * q + 2 * u]; ay[u] += bias[8 * q + 2 * u + 1]; }
        if (RELU) { ax[u] = fmaxf(ax[u], 0.0f); ay[u] = fmaxf(ay[u], 0.0f); }
    }
    uint4 o;
    o.x = f2_to_h2(ax[0], ay[0]);
    o.y = f2_to_h2(ax[1], ay[1]);
    o.z = f2_to_h2(ax[2], ay[2]);
    o.w = f2_to_h2(ax[3], ay[3]);
    out[(size_t)v * TPN + q] = o;
}

// ---------------- fused L4 agg + L5 gemm (R12 verbatim) ----------------
__global__ __launch_bounds__(256) void agg_l4l5_kernel(const uint* __restrict__ in_,
                                                       const float* __restrict__ dinv,
                                                       const int* __restrict__ rowptr,
                                                       const int* __restrict__ cnt,
                                                       const int* __restrict__ srcs,
                                                       const float* __restrict__ b4,
                                                       const float* __restrict__ W5,
                                                       float* __restrict__ outf, int n) {
    const uint4* in = (const uint4*)in_;
    int gid = blockIdx.x * 256 + threadIdx.x;
    int v = gid >> 2, q = gid & 3;
    if (v >= n) return;   // 4 | 256: node groups never split, shfl-safe
    float ax[4], ay[4];
    {
        uint4 s0 = in[(size_t)v * 4 + q];
        uint su[4] = {s0.x, s0.y, s0.z, s0.w};
#pragma unroll
        for (int u = 0; u < 4; ++u) { float2 f = h2_to_f2(su[u]); ax[u] = f.x; ay[u] = f.y; }
    }
    int start = rowptr[v];
    int len = cnt[v];
    int k = 0;
    for (; k + 4 <= len; k += 4) {
        int sA = srcs[start + k];
        int sB = srcs[start + k + 1];
        int sC = srcs[start + k + 2];
        int sD = srcs[start + k + 3];
        uint4 fA = in[(size_t)sA * 4 + q];
        uint4 fB = in[(size_t)sB * 4 + q];
        uint4 fC = in[(size_t)sC * 4 + q];
        uint4 fD = in[(size_t)sD * 4 + q];
        uint ua[4] = {fA.x, fA.y, fA.z, fA.w};
        uint ub[4] = {fB.x, fB.y, fB.z, fB.w};
        uint uc[4] = {fC.x, fC.y, fC.z, fC.w};
        uint ud[4] = {fD.x, fD.y, fD.z, fD.w};
#pragma unroll
        for (int u = 0; u < 4; ++u) {
            float2 a = h2_to_f2(ua[u]);
            float2 b = h2_to_f2(ub[u]);
            float2 c = h2_to_f2(uc[u]);
            float2 d = h2_to_f2(ud[u]);
            ax[u] += (a.x + b.x) + (c.x + d.x);
            ay[u] += (a.y + b.y) + (c.y + d.y);
        }
    }
    for (; k < len; ++k) {
        int s = srcs[start + k];
        uint4 f = in[(size_t)s * 4 + q];
        uint uu[4] = {f.x, f.y, f.z, f.w};
#pragma unroll
        for (int u = 0; u < 4; ++u) { float2 t = h2_to_f2(uu[u]); ax[u] += t.x; ay[u] += t.y; }
    }
    float dv = dinv[v];
    float feat[8];
#pragma unroll
    for (int u = 0; u < 4; ++u) {
        float fx = ax[u] * dv + b4[8 * q + 2 * u];
        float fy = ay[u] * dv + b4[8 * q + 2 * u + 1];
        feat[2 * u]     = fmaxf(fx, 0.0f);
        feat[2 * u + 1] = fmaxf(fy, 0.0f);
    }
    // L5 partial: p_c = sum_{m} feat[m] * W5[(8q+m)*3 + c]  (W5 32x3, L2-hot)
    float p0 = 0.f, p1 = 0.f, p2 = 0.f;
#pragma unroll
    for (int m = 0; m < 8; ++m) {
        int j = 8 * q + m;
        p0 = fmaf(feat[m], W5[j * 3 + 0], p0);
        p1 = fmaf(feat[m], W5[j * 3 + 1], p1);
        p2 = fmaf(feat[m], W5[j * 3 + 2], p2);
    }
#pragma unroll
    for (int m = 1; m < 4; m <<= 1) {
        p0 += __shfl_xor(p0, m, 4);
        p1 += __shfl_xor(p1, m, 4);
        p2 += __shfl_xor(p2, m, 4);
    }
    float o = (q == 0) ? p0 : (q == 1 ? p1 : (q == 2 ? p2 : 0.0f));
    outf[(size_t)v * 4 + q] = (q < 3) ? o * dv : 0.0f;   // dinv prescale for final agg
}

// ---------------- half GEMM: fp32 accumulate, packed-half out (plain loads) ----------------
template <int DIN, int DOUT, int DOUTH2, bool HAS_BIAS, bool RELU, bool SCALE>
__global__ __launch_bounds__(256) void gemm_h_kernel(const uint* __restrict__ xin,
                                                     const float* __restrict__ W,
                                                     const float* __restrict__ bias,
                                                     const float* __restrict__ dinv,
                                                     uint* __restrict__ xout,
                                                     int istride_u, int ostride, int n) {
    __shared__ float wlds[DIN * DOUT];
    for (int i = threadIdx.x; i < DIN * DOUT; i += 256) wlds[i] = W[i];
    __syncthreads();
    int gid = blockIdx.x * 256 + threadIdx.x;
    int v = gid / DOUTH2, j2 = gid % DOUTH2;
    if (v >= n) return;
    int j1 = 2 * j2;
    const uint* xr = xin + (size_t)v * istride_u;
    float acc0 = 0.0f, acc1 = 0.0f;
#pragma unroll
    for (int ku = 0; ku < DIN / 2; ++ku) {
        float2 xf = h2_to_f2(xr[ku]);
        int k = 2 * ku;
        acc0 = fmaf(xf.x, wlds[k * DOUT + j1], acc0);
        acc0 = fmaf(xf.y, wlds[(k + 1) * DOUT + j1], acc0);
        if (j1 + 1 < DOUT) {
            acc1 = fmaf(xf.x, wlds[k * DOUT + j1 + 1], acc1);
            acc1 = fmaf(xf.y, wlds[(k + 1) * DOUT + j1 + 1], acc1);
        }
    }
    if (HAS_BIAS) {
        acc0 += bias[j1];
        if (j1 + 1 < DOUT) acc1 += bias[j1 + 1];
    }
    if (RELU) { acc0 = fmaxf(acc0, 0.0f); acc1 = fmaxf(acc1, 0.0f); }
    if (SCALE) { float dv = dinv[v]; acc0 *= dv; acc1 *= dv; }
    xout[(size_t)v * ostride + j2] = f2_to_h2(acc0, acc1);
}

// ---------------- R13 fused L3 gemm + L4 gemm: LDS-issue optimized ----------------
// 64 nodes/block, 4 nodes/thread. Weights k-chunk-major as float4 (b128 LDS
// reads); per-thread column set {j2, j2+16, j2+32, j2+48} -> weight-read banks
// 2-way (free). h staged fp32 in hb4 with chunk-XOR swizzle (kc ^ (node&7))
// -> phase-2 hb reads conflict-free. Per-column fp32 accumulation order (k
// ascending, both phases) and rn rounding identical to R11 gemm34.
__global__ __launch_bounds__(256) void gemm34_kernel(const uint* __restrict__ xin,   // stride 32 uints
                                                     const float* __restrict__ W3,  // 64x64
                                                     const float* __restrict__ b3,
                                                     const float* __restrict__ W4,  // 64x32
                                                     const float* __restrict__ dinv,
                                                     uint* __restrict__ xout,       // stride 16 uints
                                                     int n) {
    __shared__ float4 w3c[16][64];   // [kc][col]: k-chunk-major, 16KB
    __shared__ float4 w4c[16][32];   // 8KB
    __shared__ float4 hb4[64][16];   // h, chunk-swizzled: [node][kc ^ (node&7)], 16KB
    for (int idx = threadIdx.x; idx < 16 * 64; idx += 256) {
        int kc = idx >> 6, c = idx & 63;
        w3c[kc][c] = make_float4(W3[(4 * kc + 0) * 64 + c], W3[(4 * kc + 1) * 64 + c],
                                 W3[(4 * kc + 2) * 64 + c], W3[(4 * kc + 3) * 64 + c]);
    }
    for (int idx = threadIdx.x; idx < 16 * 32; idx += 256) {
        int kc = idx >> 5, c = idx & 31;
        w4c[kc][c] = make_float4(W4[(4 * kc + 0) * 32 + c], W4[(4 * kc + 1) * 32 + c],
                                 W4[(4 * kc + 2) * 32 + c], W4[(4 * kc + 3) * 32 + c]);
    }
    __syncthreads();
    int r  = threadIdx.x >> 4;     // thread row 0..15
    int j2 = threadIdx.x & 15;     // column lane 0..15
    int vbase = blockIdx.x * 64;
    int li[4]; int vv[4]; bool ok[4];
#pragma unroll
    for (int t = 0; t < 4; ++t) { li[t] = r + 16 * t; vv[t] = vbase + li[t]; ok[t] = vv[t] < n; }

    // phase 1: h[c] = relu(x @ W3 + b3) for c in {j2, j2+16, j2+32, j2+48}, 4 nodes
    float acc[4][4];
#pragma unroll
    for (int t = 0; t < 4; ++t)
#pragma unroll
        for (int u = 0; u < 4; ++u) acc[t][u] = 0.0f;

    for (int kb = 0; kb < 8; ++kb) {     // 8 halves of x per kb (k = 8kb..8kb+7)
        uint4 xa[4];
#pragma unroll
        for (int t = 0; t < 4; ++t)
            xa[t] = ok[t] ? ((const uint4*)(xin + (size_t)vv[t] * 32))[kb]
                          : make_uint4(0u, 0u, 0u, 0u);
        float xf[4][8];
#pragma unroll
        for (int t = 0; t < 4; ++t) {
            float2 f0 = h2_to_f2(xa[t].x);
            float2 f1 = h2_to_f2(xa[t].y);
            float2 f2 = h2_to_f2(xa[t].z);
            float2 f3 = h2_to_f2(xa[t].w);
            xf[t][0] = f0.x; xf[t][1] = f0.y;
            xf[t][2] = f1.x; xf[t][3] = f1.y;
            xf[t][4] = f2.x; xf[t][5] = f2.y;
            xf[t][6] = f3.x; xf[t][7] = f3.y;
        }
#pragma unroll
        for (int u = 0; u < 4; ++u) {
            int c = j2 + 16 * u;
            float4 wa = w3c[2 * kb][c];       // k = 8kb..8kb+3
            float4 wb = w3c[2 * kb + 1][c];   // k = 8kb+4..8kb+7
#pragma unroll
            for (int t = 0; t < 4; ++t) {
                acc[t][u] = fmaf(xf[t][0], wa.x, acc[t][u]);
                acc[t][u] = fmaf(xf[t][1], wa.y, acc[t][u]);
                acc[t][u] = fmaf(xf[t][2], wa.z, acc[t][u]);
                acc[t][u] = fmaf(xf[t][3], wa.w, acc[t][u]);
                acc[t][u] = fmaf(xf[t][4], wb.x, acc[t][u]);
                acc[t][u] = fmaf(xf[t][5], wb.y, acc[t][u]);
                acc[t][u] = fmaf(xf[t][6], wb.z, acc[t][u]);
                acc[t][u] = fmaf(xf[t][7], wb.w, acc[t][u]);
            }
        }
    }
    // bias + relu -> hb4 (chunk-swizzled scalar writes)
#pragma unroll
    for (int u = 0; u < 4; ++u) {
        int c = j2 + 16 * u;
        float bc = b3[c];
#pragma unroll
        for (int t = 0; t < 4; ++t) {
            float h = fmaxf(acc[t][u] + bc, 0.0f);
            int pos = (c >> 2) ^ (li[t] & 7);
            ((float*)hb4)[li[t] * 64 + pos * 4 + (c & 3)] = h;
        }
    }
    __syncthreads();

    // phase 2: y[c] = (h @ W4) * dinv for c in {j2, j2+16}, 4 nodes
    float acc2[4][2];
#pragma unroll
    for (int t = 0; t < 4; ++t) { acc2[t][0] = 0.0f; acc2[t][1] = 0.0f; }
    for (int kc = 0; kc < 16; ++kc) {
        float4 wlo = w4c[kc][j2];
        float4 whi = w4c[kc][j2 + 16];
#pragma unroll
        for (int t = 0; t < 4; ++t) {
            float4 h4 = hb4[li[t]][kc ^ (li[t] & 7)];
            acc2[t][0] = fmaf(h4.x, wlo.x, acc2[t][0]);
            acc2[t][0] = fmaf(h4.y, wlo.y, acc2[t][0]);
            acc2[t][0] = fmaf(h4.z, wlo.z, acc2[t][0]);
            acc2[t][0] = fmaf(h4.w, wlo.w, acc2[t][0]);
            acc2[t][1] = fmaf(h4.x, whi.x, acc2[t][1]);
            acc2[t][1] = fmaf(h4.y, whi.y, acc2[t][1]);
            acc2[t][1] = fmaf(h4.z, whi.z, acc2[t][1]);
            acc2[t][1] = fmaf(h4.w, whi.w, acc2[t][1]);
        }
    }
#pragma unroll
    for (int t = 0; t < 4; ++t) {
        if (ok[t]) {
            float dv = dinv[vv[t]];
            __half* o = (__half*)(xout + (size_t)vv[t] * 16);
            o[j2]      = __float2half(acc2[t][0] * dv);
            o[j2 + 16] = __float2half(acc2[t][1] * dv);
        }
    }
}

// ---------------- fp32 final aggregation (R12 verbatim: 1 thread/node, float4 gathers) --------
__global__ __launch_bounds__(256) void agg_f4_kernel(const float* __restrict__ in_,
                                                     const float* __restrict__ dinv,
                                                     const int* __restrict__ rowptr,
                                                     const int* __restrict__ cnt,
                                                     const int* __restrict__ srcs,
                                                     const float* __restrict__ b,
                                                     float* __restrict__ out, int n) {
    const float4* in = (const float4*)in_;
    int v = blockIdx.x * 256 + threadIdx.x;
    if (v >= n) return;
    float4 s = in[v];
    float a0 = s.x, a1 = s.y, a2 = s.z;   // elem 3 is zero-filled by agg_l4l5
    int start = rowptr[v];
    int len = cnt[v];
    int k = 0;
    for (; k + 4 <= len; k += 4) {
        int sA = srcs[start + k];
        int sB = srcs[start + k + 1];
        int sC = srcs[start + k + 2];
        int sD = srcs[start + k + 3];
        float4 fA = in[sA];
        float4 fB = in[sB];
        float4 fC = in[sC];
        float4 fD = in[sD];
        a0 += (fA.x + fB.x) + (fC.x + fD.x);
        a1 += (fA.y + fB.y) + (fC.y + fD.y);
        a2 += (fA.z + fB.z) + (fC.z + fD.z);
    }
    for (; k < len; ++k) {
        float4 f = in[srcs[start + k]];
        a0 += f.x; a1 += f.y; a2 += f.z;
    }
    float dv = dinv[v];
    out[(size_t)v * 3 + 0] = a0 * dv + b[0];
    out[(size_t)v * 3 + 1] = a1 * dv + b[1];
    out[(size_t)v * 3 + 2] = a2 * dv + b[2];
}

// ---------------- driver ----------------

extern "C" void kernel_launch(void* const* d_in, const int* in_sizes, int n_in,
                              void* d_out, int out_size, void* d_ws, size_t ws_size,
                              hipStream_t stream) {
    const float* coords = (const float*)d_in[0];
    const int* at       = (const int*)d_in[1];
    const int* ei       = (const int*)d_in[2];
    const float* emb    = (const float*)d_in[3];
    const float* W1 = (const float*)d_in[4];  const float* b1 = (const float*)d_in[5];
    const float* W2 = (const float*)d_in[6];  const float* b2 = (const float*)d_in[7];
    const float* W3 = (const float*)d_in[8];  const float* b3 = (const float*)d_in[9];
    const float* W4 = (const float*)d_in[10]; const float* b4 = (const float*)d_in[11];
    const float* W5 = (const float*)d_in[12]; const float* b5 = (const float*)d_in[13];
    float* out = (float*)d_out;

    const int n = in_sizes[0] / 3;   // 100000
    const int e = in_sizes[2] / 2;   // 3200000
    const int* src = ei;
    const int* dst = ei + e;

    // workspace layout (pairs dies before feature buffers are born -> alias)
    char* ws = (char*)d_ws;
    size_t off = 0;
    float* dinv   = (float*)(ws + off); off += (size_t)n * 4;
    int*   cnt    = (int*)(ws + off);   off += (size_t)n * 4;
    int*   rowptr = (int*)(ws + off);   off += (size_t)n * 4;
    int*   blkcnt = (int*)(ws + off);   off += (size_t)NBLK_BIN * NBKT * 4;
    int*   srcs   = (int*)(ws + off);   off += (size_t)e * 4;
    char*  alias  = ws + off;           // max(pairs 51.4MB, A_h+B_h+B_f 27.2MB); 16B aligned
    int2*  pairs  = (int2*)alias;
    uint*  A_h    = (uint*)alias;                    // n x 32 uints
    uint*  B_h    = A_h + (size_t)n * 32;            // n x 32 uints
    float* B_f    = (float*)(B_h + (size_t)n * 32);  // n x 4 floats

    int nb = (n + 255) / 256;   // 391

    // ---- CSR build (R6 output structure; fill 1024-thr with in-block base) ----
    bin_kernel<<<NBLK_BIN, 1024, 0, stream>>>(src, dst, pairs, blkcnt, e);
    fill_kernel<<<NBKT, 1024, 0, stream>>>(pairs, blkcnt, srcs, cnt, rowptr, dinv, n);

    // ---- x0 (pre-scaled by dinv), half stride 4 uints, in A_h ----
    build_x0_h_kernel<<<nb, 256, 0, stream>>>(coords, at, emb, dinv, A_h, n);

    auto blocks = [](long long threads) { return (int)((threads + 255) / 256); };

    // L1: 6->32. agg rows 16B (TPN=1); gemm + bias + relu + dinv-prescale
    agg_v4_kernel<1, false, false><<<blocks((long long)n), 256, 0, stream>>>(
        A_h, dinv, rowptr, cnt, srcs, nullptr, B_h, n);
    gemm_h_kernel<6, 32, 16, true, true, true><<<blocks((long long)n * 16), 256, 0, stream>>>(
        B_h, W1, b1, dinv, A_h, 4, 16, n);

    // L2: 32->64. agg rows 64B (TPN=4); gemm + bias + relu + dinv-prescale
    agg_v4_kernel<4, false, false><<<blocks((long long)n * 4), 256, 0, stream>>>(
        A_h, dinv, rowptr, cnt, srcs, nullptr, B_h, n);
    gemm_h_kernel<32, 64, 32, true, true, true><<<blocks((long long)n * 32), 256, 0, stream>>>(
        B_h, W2, b2, dinv, A_h, 16, 32, n);

    // L3: 64->64 agg rows 128B (TPN=8); then fused (relu(xW3+b3) @ W4) * dinv
    agg_v4_kernel<8, false, false><<<blocks((long long)n * 8), 256, 0, stream>>>(
        A_h, dinv, rowptr, cnt, srcs, nullptr, B_h, n);
    gemm34_kernel<<<(n + 63) / 64, 256, 0, stream>>>(
        B_h, W3, b3, W4, dinv, A_h, n);

    // L4+L5 fused: agg rows 64B (TPN=4) + b4 + relu, then xW5*dinv -> B_f
    agg_l4l5_kernel<<<blocks((long long)n * 4), 256, 0, stream>>>(
        A_h, dinv, rowptr, cnt, srcs, b4, W5, B_f, n);

    // final: agg over B_f (float4, 1 thread/node) + b5 -> out
    agg_f4_kernel<<<blocks((long long)n), 256, 0, stream>>>(
        B_f, dinv, rowptr, cnt, srcs, b5, out, n);
}

// Round 6
// 412.729 us; speedup vs baseline: 1.0448x; 1.0448x over previous
//
#include <hip/hip_runtime.h>
#include <hip/hip_fp16.h>

// ---- R6 CSR-build constants (verbatim; load-bearing for agg locality) ----
#define NBLK_BIN 256   // bin blocks; chunking identical to r3/r5/r6 -> same per-cell counts
#define NBKT 196       // ceil(100000/512) dst-buckets
#define BWIN 512       // nodes per bucket
#define CAP 128        // slots per (block,bucket); lambda=63.8, +8 sigma -> no overflow

// NOTE (R8/R9): R6's exact CSR build is load-bearing. Keep CSR output EXACT.
// NOTE (R10): no __builtin_nontemporal anywhere (srcs/gemm-input have L1 reuse).
// R11 (WIN -22us): gemm34 fusion + L4L5 fusion.
// R12 (WIN -4.5us + bottleneck flip): uint4 agg gathers; aggs all <56us.
// R13 (FAILED +5us): 4-nodes/thread gemm34 -> VGPR 200, occupancy 9%, latency-
// bound. Lesson: LDS-issue fix must not cost occupancy (Guideline 6).
// R14: same fix, R11's wave structure kept (1 node/thread, 16 nodes/block,
// 4 acc/thread): k-chunk-major float4 weights ({j2,j2+16,j2+32,j2+48} cols,
// 2-way banks = free), padded hb4[16][17] f4 h-stage (conflict-free reads),
// uint4 x loads. 448 b32 -> ~112 b128 LDS reads/thread. Per-column fp32
// k-ascending accumulation preserved -> numerics bit-identical.

typedef unsigned int uint;

union U32H2 { uint u; __half2 h; };

__device__ inline float2 h2_to_f2(uint u) {
    U32H2 c; c.u = u;
    return __half22float2(c.h);
}
__device__ inline uint f2_to_h2(float a, float b) {
    U32H2 c; c.h = __floats2half2_rn(a, b);
    return c.u;
}

// ---------------- CSR build: bin pass (R6 verbatim: 1024 thr, no global atomics) ----------------
__global__ __launch_bounds__(1024) void bin_kernel(const int* __restrict__ src,
                                                   const int* __restrict__ dst,
                                                   int2* __restrict__ pairs,
                                                   int* __restrict__ blkcnt, int e) {
    __shared__ int lcnt[NBKT];
    int blk = blockIdx.x, tid = threadIdx.x;
    for (int t = tid; t < NBKT; t += 1024) lcnt[t] = 0;
    __syncthreads();
    int chunk = (e + NBLK_BIN - 1) / NBLK_BIN;
    int base = blk * chunk;
    int end = min(e, base + chunk);
    for (int i = base + tid; i < end; i += 1024) {
        int s = src[i], d = dst[i];
        int b = d >> 9;
        int pos = atomicAdd(&lcnt[b], 1);
        if (pos < CAP) pairs[((size_t)blk * NBKT + b) * CAP + pos] = make_int2(s, d);
    }
    __syncthreads();
    for (int t = tid; t < NBKT; t += 1024) blkcnt[blk * NBKT + t] = min(lcnt[t], CAP);
}

// ---------------- fused fill: in-block bucket base + counts + scan + cnt/rowptr/dinv + srcs ----
__global__ __launch_bounds__(1024) void fill_kernel(const int2* __restrict__ pairs,
                                                    const int* __restrict__ blkcnt,
                                                    int* __restrict__ srcs,
                                                    int* __restrict__ cnt,
                                                    int* __restrict__ rowptr,
                                                    float* __restrict__ dinv, int n) {
    __shared__ int lc[BWIN];
    __shared__ int ps[BWIN];
    __shared__ int sm[NBLK_BIN];
    __shared__ int gbase_s;
    int b = blockIdx.x, tid = threadIdx.x;
    int nbase = b << 9;
    if (tid < BWIN) lc[tid] = 0;
    for (int t = tid; t < NBLK_BIN; t += 1024) sm[t] = blkcnt[t * NBKT + b];
    if (tid == 0) gbase_s = 0;
    __syncthreads();
    // bucket base: sum over all bin-blocks of all buckets b' < b (L2-hot 200KB array)
    {
        long long tot = (long long)NBLK_BIN * b;
        int lsum = 0;
        for (long long j = tid; j < tot; j += 1024) {
            int blk = (int)(j / b);
            int bp  = (int)(j - (long long)blk * b);
            lsum += blkcnt[blk * NBKT + bp];
        }
        for (int o = 32; o > 0; o >>= 1) lsum += __shfl_down(lsum, o, 64);
        if ((tid & 63) == 0 && lsum != 0) atomicAdd(&gbase_s, lsum);
    }
    int wave = tid >> 6, lane = tid & 63;
    // pass 1: per-node counts (16 waves over 256 cells)
    for (int blk = wave; blk < NBLK_BIN; blk += 16) {
        int m = sm[blk];
        const int2* p = pairs + ((size_t)blk * NBKT + b) * CAP;
        for (int i = lane; i < m; i += 64) atomicAdd(&lc[p[i].y - nbase], 1);
    }
    __syncthreads();
    // exclusive scan of 512 counts
    int myc = (tid < BWIN) ? lc[tid] : 0;
    if (tid < BWIN) ps[tid] = myc;
    __syncthreads();
    for (int off = 1; off < BWIN; off <<= 1) {
        int t = 0;
        if (tid < BWIN && tid >= off) t = ps[tid - off];
        __syncthreads();
        if (tid < BWIN) ps[tid] += t;
        __syncthreads();
    }
    int gbase = gbase_s;
    if (tid < BWIN) {
        int ex = ps[tid] - myc;
        int vtx = nbase + tid;
        if (vtx < n) {
            cnt[vtx] = myc;
            rowptr[vtx] = gbase + ex;
            dinv[vtx] = rsqrtf(1.0f + (float)myc);   // +1: self-loop
        }
    }
    __syncthreads();
    if (tid < BWIN) lc[tid] = ps[tid] - myc;   // reuse as bucket-relative cursor
    __syncthreads();
    // pass 2: place srcs (contiguous monotone span for this bucket)
    for (int blk = wave; blk < NBLK_BIN; blk += 16) {
        int m = sm[blk];
        const int2* p = pairs + ((size_t)blk * NBKT + b) * CAP;
        for (int i = lane; i < m; i += 64) {
            int2 e2 = p[i];
            int o = atomicAdd(&lc[e2.y - nbase], 1);
            srcs[gbase + o] = e2.x;
        }
    }
}

// ---------------- input feature build: half, stride 4 uints, pre-scaled by dinv ----------------

__global__ __launch_bounds__(256) void build_x0_h_kernel(const float* __restrict__ coords,
                                                         const int* __restrict__ at,
                                                         const float* __restrict__ emb,
                                                         const float* __restrict__ dinv,
                                                         uint* __restrict__ x, int n) {
    int v = blockIdx.x * 256 + threadIdx.x;
    if (v >= n) return;
    float dv = dinv[v];
    float c0 = coords[3 * v + 0] * dv;
    float c1 = coords[3 * v + 1] * dv;
    float c2 = coords[3 * v + 2] * dv;
    int t = at[v];
    float e0 = emb[3 * t + 0] * dv;
    float e1 = emb[3 * t + 1] * dv;
    float e2 = emb[3 * t + 2] * dv;
    uint* row = x + (size_t)v * 4;
    row[0] = f2_to_h2(c0, c1);
    row[1] = f2_to_h2(c2, e0);
    row[2] = f2_to_h2(e1, e2);
    row[3] = 0;
}

// ---------------- R12 vectorized packed-half aggregation (verbatim) ----------------
template <int TPN, bool HAS_BIAS, bool RELU>
__global__ __launch_bounds__(256) void agg_v4_kernel(const uint* __restrict__ in_,
                                                     const float* __restrict__ dinv,
                                                     const int* __restrict__ rowptr,
                                                     const int* __restrict__ cnt,
                                                     const int* __restrict__ srcs,
                                                     const float* __restrict__ bias,
                                                     uint* __restrict__ out_, int n) {
    const uint4* in = (const uint4*)in_;
    uint4* out = (uint4*)out_;
    int gid = blockIdx.x * 256 + threadIdx.x;
    int v = gid / TPN, q = gid % TPN;
    if (v >= n) return;
    float ax[4], ay[4];
    {
        uint4 s0 = in[(size_t)v * TPN + q];
        uint su[4] = {s0.x, s0.y, s0.z, s0.w};
#pragma unroll
        for (int u = 0; u < 4; ++u) { float2 f = h2_to_f2(su[u]); ax[u] = f.x; ay[u] = f.y; }
    }
    int start = rowptr[v];
    int len = cnt[v];
    int k = 0;
    for (; k + 4 <= len; k += 4) {
        int sA = srcs[start + k];
        int sB = srcs[start + k + 1];
        int sC = srcs[start + k + 2];
        int sD = srcs[start + k + 3];
        uint4 fA = in[(size_t)sA * TPN + q];
        uint4 fB = in[(size_t)sB * TPN + q];
        uint4 fC = in[(size_t)sC * TPN + q];
        uint4 fD = in[(size_t)sD * TPN + q];
        uint ua[4] = {fA.x, fA.y, fA.z, fA.w};
        uint ub[4] = {fB.x, fB.y, fB.z, fB.w};
        uint uc[4] = {fC.x, fC.y, fC.z, fC.w};
        uint ud[4] = {fD.x, fD.y, fD.z, fD.w};
#pragma unroll
        for (int u = 0; u < 4; ++u) {
            float2 a = h2_to_f2(ua[u]);
            float2 b = h2_to_f2(ub[u]);
            float2 c = h2_to_f2(uc[u]);
            float2 d = h2_to_f2(ud[u]);
            ax[u] += (a.x + b.x) + (c.x + d.x);
            ay[u] += (a.y + b.y) + (c.y + d.y);
        }
    }
    for (; k < len; ++k) {
        int s = srcs[start + k];
        uint4 f = in[(size_t)s * TPN + q];
        uint uu[4] = {f.x, f.y, f.z, f.w};
#pragma unroll
        for (int u = 0; u < 4; ++u) { float2 t = h2_to_f2(uu[u]); ax[u] += t.x; ay[u] += t.y; }
    }
    float dv = dinv[v];
#pragma unroll
    for (int u = 0; u < 4; ++u) {
        ax[u] *= dv; ay[u] *= dv;
        if (HAS_BIAS) { ax[u] += bias[8 * q + 2 * u]; ay[u] += bias[8 * q + 2 * u + 1]; }
        if (RELU) { ax[u] = fmaxf(ax[u], 0.0f); ay[u] = fmaxf(ay[u], 0.0f); }
    }
    uint4 o;
    o.x = f2_to_h2(ax[0], ay[0]);
    o.y = f2_to_h2(ax[1], ay[1]);
    o.z = f2_to_h2(ax[2], ay[2]);
    o.w = f2_to_h2(ax[3], ay[3]);
    out[(size_t)v * TPN + q] = o;
}

// ---------------- fused L4 agg + L5 gemm (R12 verbatim) ----------------
__global__ __launch_bounds__(256) void agg_l4l5_kernel(const uint* __restrict__ in_,
                                                       const float* __restrict__ dinv,
                                                       const int* __restrict__ rowptr,
                                                       const int* __restrict__ cnt,
                                                       const int* __restrict__ srcs,
                                                       const float* __restrict__ b4,
                                                       const float* __restrict__ W5,
                                                       float* __restrict__ outf, int n) {
    const uint4* in = (const uint4*)in_;
    int gid = blockIdx.x * 256 + threadIdx.x;
    int v = gid >> 2, q = gid & 3;
    if (v >= n) return;   // 4 | 256: node groups never split, shfl-safe
    float ax[4], ay[4];
    {
        uint4 s0 = in[(size_t)v * 4 + q];
        uint su[4] = {s0.x, s0.y, s0.z, s0.w};
#pragma unroll
        for (int u = 0; u < 4; ++u) { float2 f = h2_to_f2(su[u]); ax[u] = f.x; ay[u] = f.y; }
    }
    int start = rowptr[v];
    int len = cnt[v];
    int k = 0;
    for (; k + 4 <= len; k += 4) {
        int sA = srcs[start + k];
        int sB = srcs[start + k + 1];
        int sC = srcs[start + k + 2];
        int sD = srcs[start + k + 3];
        uint4 fA = in[(size_t)sA * 4 + q];
        uint4 fB = in[(size_t)sB * 4 + q];
        uint4 fC = in[(size_t)sC * 4 + q];
        uint4 fD = in[(size_t)sD * 4 + q];
        uint ua[4] = {fA.x, fA.y, fA.z, fA.w};
        uint ub[4] = {fB.x, fB.y, fB.z, fB.w};
        uint uc[4] = {fC.x, fC.y, fC.z, fC.w};
        uint ud[4] = {fD.x, fD.y, fD.z, fD.w};
#pragma unroll
        for (int u = 0; u < 4; ++u) {
            float2 a = h2_to_f2(ua[u]);
            float2 b = h2_to_f2(ub[u]);
            float2 c = h2_to_f2(uc[u]);
            float2 d = h2_to_f2(ud[u]);
            ax[u] += (a.x + b.x) + (c.x + d.x);
            ay[u] += (a.y + b.y) + (c.y + d.y);
        }
    }
    for (; k < len; ++k) {
        int s = srcs[start + k];
        uint4 f = in[(size_t)s * 4 + q];
        uint uu[4] = {f.x, f.y, f.z, f.w};
#pragma unroll
        for (int u = 0; u < 4; ++u) { float2 t = h2_to_f2(uu[u]); ax[u] += t.x; ay[u] += t.y; }
    }
    float dv = dinv[v];
    float feat[8];
#pragma unroll
    for (int u = 0; u < 4; ++u) {
        float fx = ax[u] * dv + b4[8 * q + 2 * u];
        float fy = ay[u] * dv + b4[8 * q + 2 * u + 1];
        feat[2 * u]     = fmaxf(fx, 0.0f);
        feat[2 * u + 1] = fmaxf(fy, 0.0f);
    }
    // L5 partial: p_c = sum_{m} feat[m] * W5[(8q+m)*3 + c]  (W5 32x3, L2-hot)
    float p0 = 0.f, p1 = 0.f, p2 = 0.f;
#pragma unroll
    for (int m = 0; m < 8; ++m) {
        int j = 8 * q + m;
        p0 = fmaf(feat[m], W5[j * 3 + 0], p0);
        p1 = fmaf(feat[m], W5[j * 3 + 1], p1);
        p2 = fmaf(feat[m], W5[j * 3 + 2], p2);
    }
#pragma unroll
    for (int m = 1; m < 4; m <<= 1) {
        p0 += __shfl_xor(p0, m, 4);
        p1 += __shfl_xor(p1, m, 4);
        p2 += __shfl_xor(p2, m, 4);
    }
    float o = (q == 0) ? p0 : (q == 1 ? p1 : (q == 2 ? p2 : 0.0f));
    outf[(size_t)v * 4 + q] = (q < 3) ? o * dv : 0.0f;   // dinv prescale for final agg
}

// ---------------- half GEMM: fp32 accumulate, packed-half out (plain loads) ----------------
template <int DIN, int DOUT, int DOUTH2, bool HAS_BIAS, bool RELU, bool SCALE>
__global__ __launch_bounds__(256) void gemm_h_kernel(const uint* __restrict__ xin,
                                                     const float* __restrict__ W,
                                                     const float* __restrict__ bias,
                                                     const float* __restrict__ dinv,
                                                     uint* __restrict__ xout,
                                                     int istride_u, int ostride, int n) {
    __shared__ float wlds[DIN * DOUT];
    for (int i = threadIdx.x; i < DIN * DOUT; i += 256) wlds[i] = W[i];
    __syncthreads();
    int gid = blockIdx.x * 256 + threadIdx.x;
    int v = gid / DOUTH2, j2 = gid % DOUTH2;
    if (v >= n) return;
    int j1 = 2 * j2;
    const uint* xr = xin + (size_t)v * istride_u;
    float acc0 = 0.0f, acc1 = 0.0f;
#pragma unroll
    for (int ku = 0; ku < DIN / 2; ++ku) {
        float2 xf = h2_to_f2(xr[ku]);
        int k = 2 * ku;
        acc0 = fmaf(xf.x, wlds[k * DOUT + j1], acc0);
        acc0 = fmaf(xf.y, wlds[(k + 1) * DOUT + j1], acc0);
        if (j1 + 1 < DOUT) {
            acc1 = fmaf(xf.x, wlds[k * DOUT + j1 + 1], acc1);
            acc1 = fmaf(xf.y, wlds[(k + 1) * DOUT + j1 + 1], acc1);
        }
    }
    if (HAS_BIAS) {
        acc0 += bias[j1];
        if (j1 + 1 < DOUT) acc1 += bias[j1 + 1];
    }
    if (RELU) { acc0 = fmaxf(acc0, 0.0f); acc1 = fmaxf(acc1, 0.0f); }
    if (SCALE) { float dv = dinv[v]; acc0 *= dv; acc1 *= dv; }
    xout[(size_t)v * ostride + j2] = f2_to_h2(acc0, acc1);
}

// ---------------- R14 fused L3 gemm + L4 gemm ----------------
// R11 wave structure (16 nodes/block, 1 node/thread, 4 cols/thread) + b128 LDS:
// w3c/w4c k-chunk-major float4; cols {j2,j2+16,j2+32,j2+48} (2-way banks =
// free); hb4 padded [16][17] (phase-2 reads conflict-free: bank off = 4i+4kc).
// Per-column fp32 k-ascending accumulation == R11 -> bit-identical numerics.
#define G34_NODES 16
__global__ __launch_bounds__(256) void gemm34_kernel(const uint* __restrict__ xin,   // stride 32 uints
                                                     const float* __restrict__ W3,  // 64x64
                                                     const float* __restrict__ b3,
                                                     const float* __restrict__ W4,  // 64x32
                                                     const float* __restrict__ dinv,
                                                     uint* __restrict__ xout,       // stride 16 uints
                                                     int n) {
    __shared__ float4 w3c[16][64];   // [kc][col]: w3c[kc][c] = W3[4kc..4kc+3][c], 16KB
    __shared__ float4 w4c[16][32];   // 8KB
    __shared__ float4 hb4[16][17];   // h per node, +1 f4 pad, 4.25KB
    for (int idx = threadIdx.x; idx < 16 * 64; idx += 256) {
        int kc = idx >> 6, c = idx & 63;
        w3c[kc][c] = make_float4(W3[(4 * kc + 0) * 64 + c], W3[(4 * kc + 1) * 64 + c],
                                 W3[(4 * kc + 2) * 64 + c], W3[(4 * kc + 3) * 64 + c]);
    }
    for (int idx = threadIdx.x; idx < 16 * 32; idx += 256) {
        int kc = idx >> 5, c = idx & 31;
        w4c[kc][c] = make_float4(W4[(4 * kc + 0) * 32 + c], W4[(4 * kc + 1) * 32 + c],
                                 W4[(4 * kc + 2) * 32 + c], W4[(4 * kc + 3) * 32 + c]);
    }
    __syncthreads();
    int i  = threadIdx.x >> 4;     // local node 0..15
    int j2 = threadIdx.x & 15;     // column lane 0..15
    int v  = blockIdx.x * G34_NODES + i;
    bool ok = (v < n);

    // phase 1: h[c] = relu(x @ W3 + b3) for c in {j2, j2+16, j2+32, j2+48}
    float acc[4] = {0.f, 0.f, 0.f, 0.f};
    if (ok) {
        const uint4* xr = (const uint4*)(xin + (size_t)v * 32);
        for (int kb = 0; kb < 8; ++kb) {   // k = 8kb .. 8kb+7
            uint4 xa = xr[kb];
            float2 f0 = h2_to_f2(xa.x);
            float2 f1 = h2_to_f2(xa.y);
            float2 f2v = h2_to_f2(xa.z);
            float2 f3 = h2_to_f2(xa.w);
            float xf0 = f0.x, xf1 = f0.y, xf2 = f1.x, xf3 = f1.y;
            float xf4 = f2v.x, xf5 = f2v.y, xf6 = f3.x, xf7 = f3.y;
#pragma unroll
            for (int u = 0; u < 4; ++u) {
                int c = j2 + 16 * u;
                float4 wa = w3c[2 * kb][c];       // k = 8kb..8kb+3
                float4 wb = w3c[2 * kb + 1][c];   // k = 8kb+4..8kb+7
                acc[u] = fmaf(xf0, wa.x, acc[u]);
                acc[u] = fmaf(xf1, wa.y, acc[u]);
                acc[u] = fmaf(xf2, wa.z, acc[u]);
                acc[u] = fmaf(xf3, wa.w, acc[u]);
                acc[u] = fmaf(xf4, wb.x, acc[u]);
                acc[u] = fmaf(xf5, wb.y, acc[u]);
                acc[u] = fmaf(xf6, wb.z, acc[u]);
                acc[u] = fmaf(xf7, wb.w, acc[u]);
            }
        }
    }
#pragma unroll
    for (int u = 0; u < 4; ++u) {
        int c = j2 + 16 * u;
        float h = ok ? fmaxf(acc[u] + b3[c], 0.0f) : 0.0f;
        ((float*)hb4)[i * 68 + c] = h;    // row stride 68 words (17 f4)
    }
    __syncthreads();

    // phase 2: y[c] = (h @ W4) * dinv for c in {j2, j2+16}; k ascending via .x.y.z.w
    float a0 = 0.f, a1 = 0.f;
#pragma unroll
    for (int kc = 0; kc < 16; ++kc) {
        float4 h4  = hb4[i][kc];
        float4 wlo = w4c[kc][j2];
        float4 whi = w4c[kc][j2 + 16];
        a0 = fmaf(h4.x, wlo.x, a0);
        a0 = fmaf(h4.y, wlo.y, a0);
        a0 = fmaf(h4.z, wlo.z, a0);
        a0 = fmaf(h4.w, wlo.w, a0);
        a1 = fmaf(h4.x, whi.x, a1);
        a1 = fmaf(h4.y, whi.y, a1);
        a1 = fmaf(h4.z, whi.z, a1);
        a1 = fmaf(h4.w, whi.w, a1);
    }
    if (ok) {
        float dv = dinv[v];
        __half* o = (__half*)(xout + (size_t)v * 16);
        o[j2]      = __float2half(a0 * dv);
        o[j2 + 16] = __float2half(a1 * dv);
    }
}

// ---------------- fp32 final aggregation (R12 verbatim: 1 thread/node, float4 gathers) --------
__global__ __launch_bounds__(256) void agg_f4_kernel(const float* __restrict__ in_,
                                                     const float* __restrict__ dinv,
                                                     const int* __restrict__ rowptr,
                                                     const int* __restrict__ cnt,
                                                     const int* __restrict__ srcs,
                                                     const float* __restrict__ b,
                                                     float* __restrict__ out, int n) {
    const float4* in = (const float4*)in_;
    int v = blockIdx.x * 256 + threadIdx.x;
    if (v >= n) return;
    float4 s = in[v];
    float a0 = s.x, a1 = s.y, a2 = s.z;   // elem 3 is zero-filled by agg_l4l5
    int start = rowptr[v];
    int len = cnt[v];
    int k = 0;
    for (; k + 4 <= len; k += 4) {
        int sA = srcs[start + k];
        int sB = srcs[start + k + 1];
        int sC = srcs[start + k + 2];
        int sD = srcs[start + k + 3];
        float4 fA = in[sA];
        float4 fB = in[sB];
        float4 fC = in[sC];
        float4 fD = in[sD];
        a0 += (fA.x + fB.x) + (fC.x + fD.x);
        a1 += (fA.y + fB.y) + (fC.y + fD.y);
        a2 += (fA.z + fB.z) + (fC.z + fD.z);
    }
    for (; k < len; ++k) {
        float4 f = in[srcs[start + k]];
        a0 += f.x; a1 += f.y; a2 += f.z;
    }
    float dv = dinv[v];
    out[(size_t)v * 3 + 0] = a0 * dv + b[0];
    out[(size_t)v * 3 + 1] = a1 * dv + b[1];
    out[(size_t)v * 3 + 2] = a2 * dv + b[2];
}

// ---------------- driver ----------------

extern "C" void kernel_launch(void* const* d_in, const int* in_sizes, int n_in,
                              void* d_out, int out_size, void* d_ws, size_t ws_size,
                              hipStream_t stream) {
    const float* coords = (const float*)d_in[0];
    const int* at       = (const int*)d_in[1];
    const int* ei       = (const int*)d_in[2];
    const float* emb    = (const float*)d_in[3];
    const float* W1 = (const float*)d_in[4];  const float* b1 = (const float*)d_in[5];
    const float* W2 = (const float*)d_in[6];  const float* b2 = (const float*)d_in[7];
    const float* W3 = (const float*)d_in[8];  const float* b3 = (const float*)d_in[9];
    const float* W4 = (const float*)d_in[10]; const float* b4 = (const float*)d_in[11];
    const float* W5 = (const float*)d_in[12]; const float* b5 = (const float*)d_in[13];
    float* out = (float*)d_out;

    const int n = in_sizes[0] / 3;   // 100000
    const int e = in_sizes[2] / 2;   // 3200000
    const int* src = ei;
    const int* dst = ei + e;

    // workspace layout (pairs dies before feature buffers are born -> alias)
    char* ws = (char*)d_ws;
    size_t off = 0;
    float* dinv   = (float*)(ws + off); off += (size_t)n * 4;
    int*   cnt    = (int*)(ws + off);   off += (size_t)n * 4;
    int*   rowptr = (int*)(ws + off);   off += (size_t)n * 4;
    int*   blkcnt = (int*)(ws + off);   off += (size_t)NBLK_BIN * NBKT * 4;
    int*   srcs   = (int*)(ws + off);   off += (size_t)e * 4;
    char*  alias  = ws + off;           // max(pairs 51.4MB, A_h+B_h+B_f 27.2MB); 16B aligned
    int2*  pairs  = (int2*)alias;
    uint*  A_h    = (uint*)alias;                    // n x 32 uints
    uint*  B_h    = A_h + (size_t)n * 32;            // n x 32 uints
    float* B_f    = (float*)(B_h + (size_t)n * 32);  // n x 4 floats

    int nb = (n + 255) / 256;   // 391

    // ---- CSR build (R6 output structure; fill 1024-thr with in-block base) ----
    bin_kernel<<<NBLK_BIN, 1024, 0, stream>>>(src, dst, pairs, blkcnt, e);
    fill_kernel<<<NBKT, 1024, 0, stream>>>(pairs, blkcnt, srcs, cnt, rowptr, dinv, n);

    // ---- x0 (pre-scaled by dinv), half stride 4 uints, in A_h ----
    build_x0_h_kernel<<<nb, 256, 0, stream>>>(coords, at, emb, dinv, A_h, n);

    auto blocks = [](long long threads) { return (int)((threads + 255) / 256); };

    // L1: 6->32. agg rows 16B (TPN=1); gemm + bias + relu + dinv-prescale
    agg_v4_kernel<1, false, false><<<blocks((long long)n), 256, 0, stream>>>(
        A_h, dinv, rowptr, cnt, srcs, nullptr, B_h, n);
    gemm_h_kernel<6, 32, 16, true, true, true><<<blocks((long long)n * 16), 256, 0, stream>>>(
        B_h, W1, b1, dinv, A_h, 4, 16, n);

    // L2: 32->64. agg rows 64B (TPN=4); gemm + bias + relu + dinv-prescale
    agg_v4_kernel<4, false, false><<<blocks((long long)n * 4), 256, 0, stream>>>(
        A_h, dinv, rowptr, cnt, srcs, nullptr, B_h, n);
    gemm_h_kernel<32, 64, 32, true, true, true><<<blocks((long long)n * 32), 256, 0, stream>>>(
        B_h, W2, b2, dinv, A_h, 16, 32, n);

    // L3: 64->64 agg rows 128B (TPN=8); then fused (relu(xW3+b3) @ W4) * dinv
    agg_v4_kernel<8, false, false><<<blocks((long long)n * 8), 256, 0, stream>>>(
        A_h, dinv, rowptr, cnt, srcs, nullptr, B_h, n);
    gemm34_kernel<<<(n + G34_NODES - 1) / G34_NODES, 256, 0, stream>>>(
        B_h, W3, b3, W4, dinv, A_h, n);

    // L4+L5 fused: agg rows 64B (TPN=4) + b4 + relu, then xW5*dinv -> B_f
    agg_l4l5_kernel<<<blocks((long long)n * 4), 256, 0, stream>>>(
        A_h, dinv, rowptr, cnt, srcs, b4, W5, B_f, n);

    // final: agg over B_f (float4, 1 thread/node) + b5 -> out
    agg_f4_kernel<<<blocks((long long)n), 256, 0, stream>>>(
        B_f, dinv, rowptr, cnt, srcs, b5, out, n);
}